// Round 5
// baseline (390.293 us; speedup 1.0000x reference)
//
#include <hip/hip_runtime.h>

#define VDIM 20000
#define EDIM 128
#define BATCH 64
#define SEQ 100

typedef float f32x4 __attribute__((ext_vector_type(4)));
typedef short bf16x8 __attribute__((ext_vector_type(8)));
typedef unsigned short ushortx8 __attribute__((ext_vector_type(8)));

__device__ __forceinline__ unsigned short f2bf(float f) {
  unsigned u = __builtin_bit_cast(unsigned, f);
  u += 0x7FFFu + ((u >> 16) & 1u);   // RTNE
  return (unsigned short)(u >> 16);
}

// ---- fused prep: W->bf16 conversion (blocks 0..2499) + A gather (2500..2627)
__global__ void prep_kernel(const float* __restrict__ Wi, const float* __restrict__ Wu,
                            const int* __restrict__ attr_item, const int* __restrict__ attr_user,
                            const int* __restrict__ item_ids, const int* __restrict__ user_ids,
                            const float* __restrict__ item_emb, const float* __restrict__ user_emb,
                            unsigned short* __restrict__ wbf, unsigned short* __restrict__ abf) {
  const int bid = blockIdx.x, t = threadIdx.x;
  if (bid < 2500) {
    const int c = bid & 1;
    const float* src = c ? Wu : Wi;
    unsigned short* dst = wbf + (size_t)c * (VDIM * EDIM);
    const int i0 = ((bid >> 1) * 256 + t) * 8;
    float4 a = *(const float4*)(src + i0);
    float4 b = *(const float4*)(src + i0 + 4);
    ushortx8 o;
    o[0] = f2bf(a.x); o[1] = f2bf(a.y); o[2] = f2bf(a.z); o[3] = f2bf(a.w);
    o[4] = f2bf(b.x); o[5] = f2bf(b.y); o[6] = f2bf(b.z); o[7] = f2bf(b.w);
    *(ushortx8*)(dst + i0) = o;
  } else {
    const int g = bid - 2500;
    const int b = g & 63, c = g >> 6;
    const int r = t >> 1, h = t & 1;
    const int* ids = c ? attr_user : attr_item;
    const float* W = c ? Wu : Wi;
    const float* demb = c ? user_emb : item_emb;
    const int* dids = c ? user_ids : item_ids;
    unsigned short* dst = abf + (((size_t)(c * BATCH + b) * 128 + r) * EDIM) + h * 64;
    const float* src = nullptr;
    if (r < SEQ)       src = W + (size_t)ids[b * SEQ + r] * EDIM + h * 64;
    else if (r == SEQ) src = demb + (size_t)dids[b] * EDIM + h * 64;
    if (src) {
      #pragma unroll
      for (int i = 0; i < 8; ++i) {
        float4 a  = *(const float4*)(src + i * 8);
        float4 bb = *(const float4*)(src + i * 8 + 4);
        ushortx8 o;
        o[0] = f2bf(a.x);  o[1] = f2bf(a.y);  o[2] = f2bf(a.z);  o[3] = f2bf(a.w);
        o[4] = f2bf(bb.x); o[5] = f2bf(bb.y); o[6] = f2bf(bb.z); o[7] = f2bf(bb.w);
        *(ushortx8*)(dst + i * 8) = o;
      }
    } else {
      ushortx8 z = {0, 0, 0, 0, 0, 0, 0, 0};
      #pragma unroll
      for (int i = 0; i < 8; ++i) *(ushortx8*)(dst + i * 8) = z;
    }
  }
}

// ---- main: 256-thread blocks (4 waves: wm2 x wn2), tile 128 rows x 128 cols.
// B held in 64 VGPRs/wave (reloaded once at s==3). A (64 VGPRs/wave) loaded
// directly from pre-gathered bf16 global, prefetched one stage ahead.
// Barrier-free stage loop; per-stage LDS partial slots; ONE barrier at end.
// 256-thread block => allocator may use >128 VGPRs (m97 precedent).
__global__ __launch_bounds__(256)
void main_kernel(const unsigned short* __restrict__ wbf, const unsigned short* __restrict__ abf,
                 const float* __restrict__ tf_item, const int* __restrict__ lens_item,
                 const float* __restrict__ tf_user, const int* __restrict__ lens_user,
                 float* __restrict__ out) {
  __shared__ float sDen[8][2][128];
  __shared__ float sNum[8][2][128];
  __shared__ float sDir[8][128];

  const int t = threadIdx.x;
  const int v0 = blockIdx.x * 128;         // 157 v-tiles
  const int bg4 = blockIdx.y * 4;          // 16 b-groups
  const int lane = t & 63, wave = t >> 6;
  const int wm = wave >> 1, wn = wave & 1;
  const int quad = lane >> 4, l15 = lane & 15;

  // ---- B fragments for cluster 0 (64 VGPRs) ----
  bf16x8 breg[4][4];
  #pragma unroll
  for (int nt = 0; nt < 4; ++nt) {
    const int v = v0 + wn * 64 + nt * 16 + l15;
    const unsigned short* p = wbf + (size_t)v * EDIM + quad * 8;
    const bool ok = (v < VDIM);
    #pragma unroll
    for (int ks = 0; ks < 4; ++ks) {
      bf16x8 z = {0, 0, 0, 0, 0, 0, 0, 0};
      breg[nt][ks] = ok ? *(const bf16x8*)(p + ks * 32) : z;
    }
  }

  // ---- A fragments for stage 0 (direct global, 64 VGPRs) ----
  const int aoff = (wm * 64 + l15) * EDIM + quad * 8;
  bf16x8 af[4][4];
  {
    const unsigned short* aB = abf + (size_t)bg4 * (128 * EDIM);
    #pragma unroll
    for (int mt = 0; mt < 4; ++mt)
      #pragma unroll
      for (int ks = 0; ks < 4; ++ks)
        af[mt][ks] = *(const bf16x8*)(aB + aoff + mt * 16 * EDIM + ks * 32);
  }

  #pragma unroll 1
  for (int s = 0; s < 8; ++s) {
    const int c = s >> 2, it = s & 3, b = bg4 + it;

    // ---- GEMM: 4x4 tiles of 16x16x32, A+B both from registers ----
    f32x4 acc[4][4];
    #pragma unroll
    for (int mt = 0; mt < 4; ++mt)
      #pragma unroll
      for (int nt = 0; nt < 4; ++nt) { f32x4 z = {0.f, 0.f, 0.f, 0.f}; acc[mt][nt] = z; }

    #pragma unroll
    for (int ks = 0; ks < 4; ++ks)
      #pragma unroll
      for (int mt = 0; mt < 4; ++mt)
        #pragma unroll
        for (int nt = 0; nt < 4; ++nt)
          acc[mt][nt] = __builtin_amdgcn_mfma_f32_16x16x32_bf16(af[mt][ks], breg[nt][ks], acc[mt][nt], 0, 0, 0);

    // prefetch next stage's A (latency hidden under epilogue VALU)
    if (s < 7) {
      const int ns = s + 1;
      const unsigned short* aB = abf + (size_t)((ns >> 2) * BATCH + bg4 + (ns & 3)) * (128 * EDIM);
      #pragma unroll
      for (int mt = 0; mt < 4; ++mt)
        #pragma unroll
        for (int ks = 0; ks < 4; ++ks)
          af[mt][ks] = *(const bf16x8*)(aB + aoff + mt * 16 * EDIM + ks * 32);
    }
    // reload B for cluster 1 once (latency hidden under epilogue)
    if (s == 3) {
      const unsigned short* wb1 = wbf + (size_t)VDIM * EDIM;
      #pragma unroll
      for (int nt = 0; nt < 4; ++nt) {
        const int v = v0 + wn * 64 + nt * 16 + l15;
        const unsigned short* p = wb1 + (size_t)v * EDIM + quad * 8;
        const bool ok = (v < VDIM);
        #pragma unroll
        for (int ks = 0; ks < 4; ++ks) {
          bf16x8 z = {0, 0, 0, 0, 0, 0, 0, 0};
          breg[nt][ks] = ok ? *(const bf16x8*)(p + ks * 32) : z;
        }
      }
    }

    // ---- epilogue: softmax partials into this stage's LDS slot ----
    const float* tf = c ? tf_user : tf_item;
    const int* ln = c ? lens_user : lens_item;
    const int lenb = ln[b];
    float wv[4][4];
    #pragma unroll
    for (int mt = 0; mt < 4; ++mt)
      #pragma unroll
      for (int r = 0; r < 4; ++r) {
        const int row = wm * 64 + mt * 16 + quad * 4 + r;
        wv[mt][r] = (row < lenb) ? tf[b * SEQ + row] : 0.f;
      }

    #pragma unroll
    for (int nt = 0; nt < 4; ++nt) {
      float den = 0.f, num = 0.f;
      #pragma unroll
      for (int mt = 0; mt < 4; ++mt)
        #pragma unroll
        for (int r = 0; r < 4; ++r) {
          const float v = acc[mt][nt][r];
          const float e = __expf(v);
          den += e;
          num = fmaf(wv[mt][r], e * v, num);
        }
      den += __shfl_xor(den, 16, 64);
      den += __shfl_xor(den, 32, 64);
      num += __shfl_xor(num, 16, 64);
      num += __shfl_xor(num, 32, 64);
      const int col = wn * 64 + nt * 16 + l15;
      if (quad == 0) {
        sDen[s][wm][col] = den;
        sNum[s][wm][col] = num;
      }
      // row 100 lives in wm==1 (rows 64..127): 100-64 = 36 -> mt2, quad1, r0
      if (wm == 1 && quad == 1) sDir[s][col] = acc[2][nt][0];
    }
  }

  __syncthreads();   // the ONLY barrier

  // ---- combine all 8 stages; thread t<128 owns column t ----
  if (t < 128) {
    float res[4] = {0.f, 0.f, 0.f, 0.f};
    #pragma unroll
    for (int s = 0; s < 8; ++s) {
      float den = sDen[s][0][t] + sDen[s][1][t];
      float num = sNum[s][0][t] + sNum[s][1][t];
      float dir = sDir[s][t];
      den -= 27.f + __expf(dir);   // 27 zero-pad rows + the direct row
      res[s & 3] += num / den + dir;
    }
    const int v = v0 + t;
    if (v < VDIM) {
      #pragma unroll
      for (int it = 0; it < 4; ++it)
        out[(size_t)(bg4 + it) * VDIM + v] = res[it];
    }
  }
}

extern "C" void kernel_launch(void* const* d_in, const int* in_sizes, int n_in,
                              void* d_out, int out_size, void* d_ws, size_t ws_size,
                              hipStream_t stream) {
  const int*   attr_item = (const int*)d_in[0];
  const float* tf_item   = (const float*)d_in[1];
  const int*   lens_item = (const int*)d_in[2];
  const int*   item_ids  = (const int*)d_in[3];
  const int*   attr_user = (const int*)d_in[4];
  const float* tf_user   = (const float*)d_in[5];
  const int*   lens_user = (const int*)d_in[6];
  const int*   user_ids  = (const int*)d_in[7];
  const float* W_item    = (const float*)d_in[8];
  const float* W_user    = (const float*)d_in[9];
  const float* user_emb  = (const float*)d_in[10];
  const float* item_emb  = (const float*)d_in[11];
  float* out = (float*)d_out;

  unsigned short* wbf = (unsigned short*)d_ws;                  // [2][V][E] bf16
  unsigned short* abf = wbf + (size_t)2 * VDIM * EDIM;          // [2][64][128][E] bf16

  prep_kernel<<<dim3(2500 + 128), 256, 0, stream>>>(W_item, W_user, attr_item, attr_user,
                                                    item_ids, user_ids, item_emb, user_emb,
                                                    wbf, abf);
  main_kernel<<<dim3(157, 16), 256, 0, stream>>>(wbf, abf, tf_item, lens_item,
                                                 tf_user, lens_user, out);
}

// Round 6
// 341.651 us; speedup vs baseline: 1.1424x; 1.1424x over previous
//
#include <hip/hip_runtime.h>

#define VDIM 20000
#define EDIM 128
#define BATCH 64
#define SEQ 100

typedef float f32x4 __attribute__((ext_vector_type(4)));
typedef short bf16x8 __attribute__((ext_vector_type(8)));
typedef unsigned short ushortx8 __attribute__((ext_vector_type(8)));

typedef __attribute__((address_space(1))) const unsigned int gas_u32;
typedef __attribute__((address_space(3))) unsigned int las_u32;

__device__ __forceinline__ void async16(unsigned short* lds, const unsigned short* g) {
  __builtin_amdgcn_global_load_lds((gas_u32*)g, (las_u32*)lds, 16, 0, 0);
}

__device__ __forceinline__ unsigned short f2bf(float f) {
  unsigned u = __builtin_bit_cast(unsigned, f);
  u += 0x7FFFu + ((u >> 16) & 1u);   // RTNE
  return (unsigned short)(u >> 16);
}

// ---- fused prep: W->bf16 (blocks 0..2499) + A gather PRE-SWIZZLED (2500..2627)
// abf layout: per (c,b) tile of 2048 16B-chunks; chunk (r,jj) holds source
// row r, 16B-chunk j = jj ^ (r&15)  -> linear DMA into LDS yields swizzled tile.
__global__ void prep_kernel(const float* __restrict__ Wi, const float* __restrict__ Wu,
                            const int* __restrict__ attr_item, const int* __restrict__ attr_user,
                            const int* __restrict__ item_ids, const int* __restrict__ user_ids,
                            const float* __restrict__ item_emb, const float* __restrict__ user_emb,
                            unsigned short* __restrict__ wbf, unsigned short* __restrict__ abf) {
  const int bid = blockIdx.x, t = threadIdx.x;
  if (bid < 2500) {
    const int c = bid & 1;
    const float* src = c ? Wu : Wi;
    unsigned short* dst = wbf + (size_t)c * (VDIM * EDIM);
    const int i0 = ((bid >> 1) * 256 + t) * 8;
    float4 a = *(const float4*)(src + i0);
    float4 b = *(const float4*)(src + i0 + 4);
    ushortx8 o;
    o[0] = f2bf(a.x); o[1] = f2bf(a.y); o[2] = f2bf(a.z); o[3] = f2bf(a.w);
    o[4] = f2bf(b.x); o[5] = f2bf(b.y); o[6] = f2bf(b.z); o[7] = f2bf(b.w);
    *(ushortx8*)(dst + i0) = o;
  } else {
    const int g = bid - 2500;
    const int b = g & 63, c = g >> 6;
    const int r = t >> 1, h = t & 1;
    const int* ids = c ? attr_user : attr_item;
    const float* W = c ? Wu : Wi;
    const float* demb = c ? user_emb : item_emb;
    const int* dids = c ? user_ids : item_ids;
    unsigned short* dst = abf + (size_t)(c * BATCH + b) * 16384;
    const float* src = nullptr;
    if (r < SEQ)       src = W + (size_t)ids[b * SEQ + r] * EDIM;
    else if (r == SEQ) src = demb + (size_t)dids[b] * EDIM;
    if (src) {
      #pragma unroll
      for (int k = 0; k < 8; ++k) {
        const int jj = h * 8 + k;
        const int j = jj ^ (r & 15);
        float4 a  = *(const float4*)(src + j * 8);
        float4 bb = *(const float4*)(src + j * 8 + 4);
        ushortx8 o;
        o[0] = f2bf(a.x);  o[1] = f2bf(a.y);  o[2] = f2bf(a.z);  o[3] = f2bf(a.w);
        o[4] = f2bf(bb.x); o[5] = f2bf(bb.y); o[6] = f2bf(bb.z); o[7] = f2bf(bb.w);
        *(ushortx8*)(dst + (r * 16 + jj) * 8) = o;
      }
    } else {
      ushortx8 z = {0, 0, 0, 0, 0, 0, 0, 0};
      #pragma unroll
      for (int k = 0; k < 8; ++k) *(ushortx8*)(dst + (r * 16 + h * 8 + k) * 8) = z;
    }
  }
}

// ---- main: 256 thr (4 waves wm2 x wn2), tile 128 rows x 128 cols.
// B register-resident (64 VGPR, reloaded at s==3); A via global_load_lds into
// double-buffered pre-swizzled LDS tiles; acc in AGPRs; one barrier per stage.
__global__ __launch_bounds__(256)
void main_kernel(const unsigned short* __restrict__ wbf, const unsigned short* __restrict__ abf,
                 const float* __restrict__ tf_item, const int* __restrict__ lens_item,
                 const float* __restrict__ tf_user, const int* __restrict__ lens_user,
                 float* __restrict__ out) {
  __shared__ __align__(16) unsigned short sA[2][16384];   // 2 x 32KB swizzled A tiles
  __shared__ float sDen[2][2][128];                       // [parity][wm][col]
  __shared__ float sNum[2][2][128];
  __shared__ float sDir[2][128];
  __shared__ float sTF[2][4][128];                        // padded to 128
  __shared__ int   sLen[2][4];
  __shared__ float sRes[4][128];                          // cluster-0 combined vals

  const int t = threadIdx.x;
  const int v0 = blockIdx.x * 128;         // 157 v-tiles
  const int bg4 = blockIdx.y * 4;          // 16 b-groups
  const int lane = t & 63, wave = t >> 6;
  const int wm = wave >> 1, wn = wave & 1;
  const int quad = lane >> 4, l15 = lane & 15;

  // ---- stage tf / lens into LDS (once per block) ----
  for (int k = t; k < 800; k += 256) {
    const int c = k / 400, r2 = k - c * 400;
    const int bi = r2 / 100, si = r2 - bi * 100;
    sTF[c][bi][si] = (c ? tf_user : tf_item)[(bg4 + bi) * SEQ + si];
  }
  if (t < 8) sLen[t >> 2][t & 3] = ((t >= 4) ? lens_user : lens_item)[bg4 + (t & 3)];

  // ---- B fragments for cluster 0 (64 VGPRs) ----
  bf16x8 breg[4][4];
  #pragma unroll
  for (int nt = 0; nt < 4; ++nt) {
    const int v = v0 + wn * 64 + nt * 16 + l15;
    const unsigned short* p = wbf + (size_t)v * EDIM + quad * 8;
    const bool ok = (v < VDIM);
    #pragma unroll
    for (int ks = 0; ks < 4; ++ks) {
      bf16x8 z = {0, 0, 0, 0, 0, 0, 0, 0};
      breg[nt][ks] = ok ? *(const bf16x8*)(p + ks * 32) : z;
    }
  }

  // ---- issue async A DMA for stage 0 ----
  {
    const unsigned short* gb = abf + (size_t)bg4 * 16384;
    #pragma unroll
    for (int i = 0; i < 8; ++i)
      async16(&sA[0][(i * 256 + wave * 64) * 8], gb + (size_t)(i * 256 + t) * 8);
  }

  #pragma unroll 1
  for (int s = 0; s < 8; ++s) {
    const int c = s >> 2, it = s & 3, buf = s & 1;

    __syncthreads();   // drains this stage's A DMA (vmcnt 0) + orders LDS

    // ---- combine previous stage's partials ----
    if (s > 0 && t < 128) {
      const int ps = s - 1, p = ps & 1, pit = ps & 3;
      float den = sDen[p][0][t] + sDen[p][1][t];
      float num = sNum[p][0][t] + sNum[p][1][t];
      float dir = sDir[p][t];
      den -= 27.f + __expf(dir);      // 27 zero-pad rows + direct row
      const float val = num / den + dir;
      if (ps < 4) sRes[pit][t] = val;
      else {
        const int v = v0 + t;
        if (v < VDIM) out[(size_t)(bg4 + pit) * VDIM + v] = sRes[pit][t] + val;
      }
    }

    // ---- issue next stage's A DMA into the other buffer ----
    if (s < 7) {
      const int ns = s + 1;
      const unsigned short* gb = abf + (size_t)((ns >> 2) * BATCH + bg4 + (ns & 3)) * 16384;
      #pragma unroll
      for (int i = 0; i < 8; ++i)
        async16(&sA[buf ^ 1][(i * 256 + wave * 64) * 8], gb + (size_t)(i * 256 + t) * 8);
    }

    // ---- GEMM: 4x4 tiles of 16x16x32; A from LDS (swizzled), B from regs ----
    f32x4 acc[4][4];
    #pragma unroll
    for (int mt = 0; mt < 4; ++mt)
      #pragma unroll
      for (int nt = 0; nt < 4; ++nt) { f32x4 z = {0.f, 0.f, 0.f, 0.f}; acc[mt][nt] = z; }

    const unsigned char* pA = (const unsigned char*)&sA[buf][0];
    #pragma unroll
    for (int ks = 0; ks < 4; ++ks) {
      const int j = ks * 4 + quad;
      const int sw = ((j ^ l15) << 4);
      bf16x8 af[4];
      #pragma unroll
      for (int mt = 0; mt < 4; ++mt)
        af[mt] = *(const bf16x8*)(pA + (wm * 64 + mt * 16 + l15) * 256 + sw);
      #pragma unroll
      for (int mt = 0; mt < 4; ++mt)
        #pragma unroll
        for (int nt = 0; nt < 4; ++nt)
          acc[mt][nt] = __builtin_amdgcn_mfma_f32_16x16x32_bf16(af[mt], breg[nt][ks], acc[mt][nt], 0, 0, 0);
    }

    // reload B for cluster 1 once (drained by s==4 barrier + reg deps)
    if (s == 3) {
      const unsigned short* wb1 = wbf + (size_t)VDIM * EDIM;
      #pragma unroll
      for (int nt = 0; nt < 4; ++nt) {
        const int v = v0 + wn * 64 + nt * 16 + l15;
        const unsigned short* p = wb1 + (size_t)v * EDIM + quad * 8;
        const bool ok = (v < VDIM);
        #pragma unroll
        for (int ks = 0; ks < 4; ++ks) {
          bf16x8 z = {0, 0, 0, 0, 0, 0, 0, 0};
          breg[nt][ks] = ok ? *(const bf16x8*)(p + ks * 32) : z;
        }
      }
    }

    // ---- epilogue: softmax partials into parity slot ----
    const int lenb = sLen[c][it];
    float wv[4][4];
    #pragma unroll
    for (int mt = 0; mt < 4; ++mt)
      #pragma unroll
      for (int r = 0; r < 4; ++r) {
        const int row = wm * 64 + mt * 16 + quad * 4 + r;
        wv[mt][r] = (row < lenb) ? sTF[c][it][row] : 0.f;
      }

    #pragma unroll
    for (int nt = 0; nt < 4; ++nt) {
      float den = 0.f, num = 0.f;
      #pragma unroll
      for (int mt = 0; mt < 4; ++mt)
        #pragma unroll
        for (int r = 0; r < 4; ++r) {
          const float v = acc[mt][nt][r];
          const float e = __expf(v);
          den += e;
          num = fmaf(wv[mt][r], e * v, num);
        }
      den += __shfl_xor(den, 16, 64);
      den += __shfl_xor(den, 32, 64);
      num += __shfl_xor(num, 16, 64);
      num += __shfl_xor(num, 32, 64);
      const int col = wn * 64 + nt * 16 + l15;
      if (quad == 0) {
        sDen[buf][wm][col] = den;
        sNum[buf][wm][col] = num;
      }
      // row 100 = wm1, mt2, quad1, r0
      if (wm == 1 && quad == 1) sDir[buf][col] = acc[2][nt][0];
    }
  }

  __syncthreads();

  // ---- combine final stage (s=7, parity 1, it=3) ----
  if (t < 128) {
    float den = sDen[1][0][t] + sDen[1][1][t];
    float num = sNum[1][0][t] + sNum[1][1][t];
    float dir = sDir[1][t];
    den -= 27.f + __expf(dir);
    const float val = num / den + dir;
    const int v = v0 + t;
    if (v < VDIM) out[(size_t)(bg4 + 3) * VDIM + v] = sRes[3][t] + val;
  }
}

extern "C" void kernel_launch(void* const* d_in, const int* in_sizes, int n_in,
                              void* d_out, int out_size, void* d_ws, size_t ws_size,
                              hipStream_t stream) {
  const int*   attr_item = (const int*)d_in[0];
  const float* tf_item   = (const float*)d_in[1];
  const int*   lens_item = (const int*)d_in[2];
  const int*   item_ids  = (const int*)d_in[3];
  const int*   attr_user = (const int*)d_in[4];
  const float* tf_user   = (const float*)d_in[5];
  const int*   lens_user = (const int*)d_in[6];
  const int*   user_ids  = (const int*)d_in[7];
  const float* W_item    = (const float*)d_in[8];
  const float* W_user    = (const float*)d_in[9];
  const float* user_emb  = (const float*)d_in[10];
  const float* item_emb  = (const float*)d_in[11];
  float* out = (float*)d_out;

  unsigned short* wbf = (unsigned short*)d_ws;                  // [2][V][E] bf16 (linear)
  unsigned short* abf = wbf + (size_t)2 * VDIM * EDIM;          // [2][64] swizzled 32KB tiles

  prep_kernel<<<dim3(2500 + 128), 256, 0, stream>>>(W_item, W_user, attr_item, attr_user,
                                                    item_ids, user_ids, item_emb, user_emb,
                                                    wbf, abf);
  main_kernel<<<dim3(157, 16), 256, 0, stream>>>(wbf, abf, tf_item, lens_item,
                                                 tf_user, lens_user, out);
}

// Round 7
// 252.353 us; speedup vs baseline: 1.5466x; 1.3539x over previous
//
#include <hip/hip_runtime.h>

#define VDIM 20000
#define EDIM 128
#define BATCH 64
#define SEQ 100

typedef float f32x4 __attribute__((ext_vector_type(4)));
typedef short bf16x8 __attribute__((ext_vector_type(8)));
typedef unsigned short ushortx8 __attribute__((ext_vector_type(8)));

typedef __attribute__((address_space(1))) const unsigned int gas_u32;
typedef __attribute__((address_space(3))) unsigned int las_u32;

__device__ __forceinline__ void async16(unsigned short* lds, const unsigned short* g) {
  __builtin_amdgcn_global_load_lds((gas_u32*)g, (las_u32*)lds, 16, 0, 0);
}

__device__ __forceinline__ unsigned short f2bf(float f) {
  unsigned u = __builtin_bit_cast(unsigned, f);
  u += 0x7FFFu + ((u >> 16) & 1u);   // RTNE
  return (unsigned short)(u >> 16);
}

// ---- fused prep: W->bf16 (blocks 0..2499) + A gather PRE-SWIZZLED (2500..2627)
// abf layout: per (c,b) tile of 2048 16B-chunks; chunk (r,jj) holds source
// row r, 16B-chunk j = jj ^ (r&15)  -> linear DMA into LDS yields swizzled tile.
__global__ void prep_kernel(const float* __restrict__ Wi, const float* __restrict__ Wu,
                            const int* __restrict__ attr_item, const int* __restrict__ attr_user,
                            const int* __restrict__ item_ids, const int* __restrict__ user_ids,
                            const float* __restrict__ item_emb, const float* __restrict__ user_emb,
                            unsigned short* __restrict__ wbf, unsigned short* __restrict__ abf) {
  const int bid = blockIdx.x, t = threadIdx.x;
  if (bid < 2500) {
    const int c = bid & 1;
    const float* src = c ? Wu : Wi;
    unsigned short* dst = wbf + (size_t)c * (VDIM * EDIM);
    const int i0 = ((bid >> 1) * 256 + t) * 8;
    float4 a = *(const float4*)(src + i0);
    float4 b = *(const float4*)(src + i0 + 4);
    ushortx8 o;
    o[0] = f2bf(a.x); o[1] = f2bf(a.y); o[2] = f2bf(a.z); o[3] = f2bf(a.w);
    o[4] = f2bf(b.x); o[5] = f2bf(b.y); o[6] = f2bf(b.z); o[7] = f2bf(b.w);
    *(ushortx8*)(dst + i0) = o;
  } else {
    const int g = bid - 2500;
    const int b = g & 63, c = g >> 6;
    const int r = t >> 1, h = t & 1;
    const int* ids = c ? attr_user : attr_item;
    const float* W = c ? Wu : Wi;
    const float* demb = c ? user_emb : item_emb;
    const int* dids = c ? user_ids : item_ids;
    unsigned short* dst = abf + (size_t)(c * BATCH + b) * 16384;
    const float* src = nullptr;
    if (r < SEQ)       src = W + (size_t)ids[b * SEQ + r] * EDIM;
    else if (r == SEQ) src = demb + (size_t)dids[b] * EDIM;
    if (src) {
      #pragma unroll
      for (int k = 0; k < 8; ++k) {
        const int jj = h * 8 + k;
        const int j = jj ^ (r & 15);
        float4 a  = *(const float4*)(src + j * 8);
        float4 bb = *(const float4*)(src + j * 8 + 4);
        ushortx8 o;
        o[0] = f2bf(a.x);  o[1] = f2bf(a.y);  o[2] = f2bf(a.z);  o[3] = f2bf(a.w);
        o[4] = f2bf(bb.x); o[5] = f2bf(bb.y); o[6] = f2bf(bb.z); o[7] = f2bf(bb.w);
        *(ushortx8*)(dst + (r * 16 + jj) * 8) = o;
      }
    } else {
      ushortx8 z = {0, 0, 0, 0, 0, 0, 0, 0};
      #pragma unroll
      for (int k = 0; k < 8; ++k) *(ushortx8*)(dst + (r * 16 + h * 8 + k) * 8) = z;
    }
  }
}

// ---- main: 256 thr (4 waves wm2 x wn2), tile 128 rows x 128 cols.
// B register-resident (64 VGPR, reloaded at s==3); A via global_load_lds into
// double-buffered pre-swizzled LDS tiles; acc in AGPRs; one barrier per stage.
// __launch_bounds__(256, 2): cap total unified regs at 256/wave so 2 waves/SIMD
// are genuinely resident (R6 ran at 1 wave/SIMD -> nothing hid the serial chain).
__global__ __launch_bounds__(256, 2)
void main_kernel(const unsigned short* __restrict__ wbf, const unsigned short* __restrict__ abf,
                 const float* __restrict__ tf_item, const int* __restrict__ lens_item,
                 const float* __restrict__ tf_user, const int* __restrict__ lens_user,
                 float* __restrict__ out) {
  __shared__ __align__(16) unsigned short sA[2][16384];   // 2 x 32KB swizzled A tiles
  __shared__ float sDen[2][2][128];                       // [parity][wm][col]
  __shared__ float sNum[2][2][128];
  __shared__ float sDir[2][128];
  __shared__ float sTF[2][4][128];                        // padded to 128
  __shared__ int   sLen[2][4];
  __shared__ float sRes[4][128];                          // cluster-0 combined vals

  const int t = threadIdx.x;
  const int v0 = blockIdx.x * 128;         // 157 v-tiles
  const int bg4 = blockIdx.y * 4;          // 16 b-groups
  const int lane = t & 63, wave = t >> 6;
  const int wm = wave >> 1, wn = wave & 1;
  const int quad = lane >> 4, l15 = lane & 15;

  // ---- stage tf / lens into LDS (once per block) ----
  for (int k = t; k < 800; k += 256) {
    const int c = k / 400, r2 = k - c * 400;
    const int bi = r2 / 100, si = r2 - bi * 100;
    sTF[c][bi][si] = (c ? tf_user : tf_item)[(bg4 + bi) * SEQ + si];
  }
  if (t < 8) sLen[t >> 2][t & 3] = ((t >= 4) ? lens_user : lens_item)[bg4 + (t & 3)];

  // ---- B fragments for cluster 0 (64 VGPRs) ----
  bf16x8 breg[4][4];
  #pragma unroll
  for (int nt = 0; nt < 4; ++nt) {
    const int v = v0 + wn * 64 + nt * 16 + l15;
    const unsigned short* p = wbf + (size_t)v * EDIM + quad * 8;
    const bool ok = (v < VDIM);
    #pragma unroll
    for (int ks = 0; ks < 4; ++ks) {
      bf16x8 z = {0, 0, 0, 0, 0, 0, 0, 0};
      breg[nt][ks] = ok ? *(const bf16x8*)(p + ks * 32) : z;
    }
  }

  // ---- issue async A DMA for stage 0 ----
  {
    const unsigned short* gb = abf + (size_t)bg4 * 16384;
    #pragma unroll
    for (int i = 0; i < 8; ++i)
      async16(&sA[0][(i * 256 + wave * 64) * 8], gb + (size_t)(i * 256 + t) * 8);
  }

  #pragma unroll 1
  for (int s = 0; s < 8; ++s) {
    const int c = s >> 2, it = s & 3, buf = s & 1;

    __syncthreads();   // drains this stage's A DMA (vmcnt 0) + orders LDS

    // ---- issue next stage's A DMA into the other buffer (early: max cover) ----
    if (s < 7) {
      const int ns = s + 1;
      const unsigned short* gb = abf + (size_t)((ns >> 2) * BATCH + bg4 + (ns & 3)) * 16384;
      #pragma unroll
      for (int i = 0; i < 8; ++i)
        async16(&sA[buf ^ 1][(i * 256 + wave * 64) * 8], gb + (size_t)(i * 256 + t) * 8);
    }

    // ---- combine previous stage's partials ----
    if (s > 0 && t < 128) {
      const int ps = s - 1, p = ps & 1, pit = ps & 3;
      float den = sDen[p][0][t] + sDen[p][1][t];
      float num = sNum[p][0][t] + sNum[p][1][t];
      float dir = sDir[p][t];
      den -= 27.f + __expf(dir);      // 27 zero-pad rows + direct row
      const float val = num / den + dir;
      if (ps < 4) sRes[pit][t] = val;
      else {
        const int v = v0 + t;
        if (v < VDIM) out[(size_t)(bg4 + pit) * VDIM + v] = sRes[pit][t] + val;
      }
    }

    // ---- GEMM: 4x4 tiles of 16x16x32; A from LDS (swizzled), B from regs ----
    f32x4 acc[4][4];
    #pragma unroll
    for (int mt = 0; mt < 4; ++mt)
      #pragma unroll
      for (int nt = 0; nt < 4; ++nt) { f32x4 z = {0.f, 0.f, 0.f, 0.f}; acc[mt][nt] = z; }

    const unsigned char* pA = (const unsigned char*)&sA[buf][0];
    #pragma unroll
    for (int ks = 0; ks < 4; ++ks) {
      const int j = ks * 4 + quad;
      const int sw = ((j ^ l15) << 4);
      bf16x8 af[4];
      #pragma unroll
      for (int mt = 0; mt < 4; ++mt)
        af[mt] = *(const bf16x8*)(pA + (wm * 64 + mt * 16 + l15) * 256 + sw);
      #pragma unroll
      for (int mt = 0; mt < 4; ++mt)
        #pragma unroll
        for (int nt = 0; nt < 4; ++nt)
          acc[mt][nt] = __builtin_amdgcn_mfma_f32_16x16x32_bf16(af[mt], breg[nt][ks], acc[mt][nt], 0, 0, 0);
    }

    // reload B for cluster 1 once (drained by s==4 barrier + reg deps)
    if (s == 3) {
      const unsigned short* wb1 = wbf + (size_t)VDIM * EDIM;
      #pragma unroll
      for (int nt = 0; nt < 4; ++nt) {
        const int v = v0 + wn * 64 + nt * 16 + l15;
        const unsigned short* p = wb1 + (size_t)v * EDIM + quad * 8;
        const bool ok = (v < VDIM);
        #pragma unroll
        for (int ks = 0; ks < 4; ++ks) {
          bf16x8 z = {0, 0, 0, 0, 0, 0, 0, 0};
          breg[nt][ks] = ok ? *(const bf16x8*)(p + ks * 32) : z;
        }
      }
    }

    // ---- epilogue: softmax partials into parity slot ----
    const int lenb = sLen[c][it];
    float wv[4][4];
    #pragma unroll
    for (int mt = 0; mt < 4; ++mt)
      #pragma unroll
      for (int r = 0; r < 4; ++r) {
        const int row = wm * 64 + mt * 16 + quad * 4 + r;
        wv[mt][r] = (row < lenb) ? sTF[c][it][row] : 0.f;
      }

    #pragma unroll
    for (int nt = 0; nt < 4; ++nt) {
      float den = 0.f, num = 0.f;
      #pragma unroll
      for (int mt = 0; mt < 4; ++mt)
        #pragma unroll
        for (int r = 0; r < 4; ++r) {
          const float v = acc[mt][nt][r];
          const float e = __expf(v);
          den += e;
          num = fmaf(wv[mt][r], e * v, num);
        }
      den += __shfl_xor(den, 16, 64);
      den += __shfl_xor(den, 32, 64);
      num += __shfl_xor(num, 16, 64);
      num += __shfl_xor(num, 32, 64);
      const int col = wn * 64 + nt * 16 + l15;
      if (quad == 0) {
        sDen[buf][wm][col] = den;
        sNum[buf][wm][col] = num;
      }
      // row 100 = wm1, mt2, quad1, r0
      if (wm == 1 && quad == 1) sDir[buf][col] = acc[2][nt][0];
    }
  }

  __syncthreads();

  // ---- combine final stage (s=7, parity 1, it=3) ----
  if (t < 128) {
    float den = sDen[1][0][t] + sDen[1][1][t];
    float num = sNum[1][0][t] + sNum[1][1][t];
    float dir = sDir[1][t];
    den -= 27.f + __expf(dir);
    const float val = num / den + dir;
    const int v = v0 + t;
    if (v < VDIM) out[(size_t)(bg4 + 3) * VDIM + v] = sRes[3][t] + val;
  }
}

extern "C" void kernel_launch(void* const* d_in, const int* in_sizes, int n_in,
                              void* d_out, int out_size, void* d_ws, size_t ws_size,
                              hipStream_t stream) {
  const int*   attr_item = (const int*)d_in[0];
  const float* tf_item   = (const float*)d_in[1];
  const int*   lens_item = (const int*)d_in[2];
  const int*   item_ids  = (const int*)d_in[3];
  const int*   attr_user = (const int*)d_in[4];
  const float* tf_user   = (const float*)d_in[5];
  const int*   lens_user = (const int*)d_in[6];
  const int*   user_ids  = (const int*)d_in[7];
  const float* W_item    = (const float*)d_in[8];
  const float* W_user    = (const float*)d_in[9];
  const float* user_emb  = (const float*)d_in[10];
  const float* item_emb  = (const float*)d_in[11];
  float* out = (float*)d_out;

  unsigned short* wbf = (unsigned short*)d_ws;                  // [2][V][E] bf16 (linear)
  unsigned short* abf = wbf + (size_t)2 * VDIM * EDIM;          // [2][64] swizzled 32KB tiles

  prep_kernel<<<dim3(2500 + 128), 256, 0, stream>>>(W_item, W_user, attr_item, attr_user,
                                                    item_ids, user_ids, item_emb, user_emb,
                                                    wbf, abf);
  main_kernel<<<dim3(157, 16), 256, 0, stream>>>(wbf, abf, tf_item, lens_item,
                                                 tf_user, lens_user, out);
}